// Round 2
// baseline (74677.484 us; speedup 1.0000x reference)
//
// Encoder-decoder LSTM + dot attention + linear, MI355X fp32.  R6
// R4 counters: scans 1622us each (82% of total); WRITE 192MB = 64MB states +
// 128MB agent publish stores; FETCH 103MB = memory-side polls. Exchange RTT
// (~3000cy/step) dominates vs ~600cy gemv. R5 (sc0 L2-local exchange) died
// with no diagnostics; R6 is the hardened retry:
//  - XCC id via __builtin_amdgcn_s_getreg(0x1814) (numeric hwreg 20, no asm name)
//  - xcc handshake slots live in out[0:512] (scratch; attn overwrites) -> ws
//    layout byte-identical to R4 (rules out ws overflow)
//  - dual publish: sc0 store (fast, L2) + agent store (slow, memory-side net)
//  - fast poll bounded at 400 spins, then agent-poll fallback -> cannot hang;
//    cross-XCD placement degrades to exact R4 behavior
//  - enc/dec share slot arrays, disambiguated by tag0 (0 / 1024)
// Predicted: scan 1622 -> 600-900us, FETCH 103 -> <20MB, total ~2100-2500us.
#include <hip/hip_runtime.h>
#include <math.h>

#define HD 256
#define GD 1024   // 4*H
#define TT 1024
#define BB 64
#define NT 512    // scan block size

__device__ __forceinline__ float sig_(float x)  { return 1.f / (1.f + __expf(-x)); }
__device__ __forceinline__ float tanh_(float x) { return 1.f - 2.f / (1.f + __expf(2.f * x)); }

// ---------------- prep: transpose Whh -> [k][j], bias sums, zero exchange ----------------
__global__ __launch_bounds__(256) void prep_kernel(
    const float* __restrict__ eW, const float* __restrict__ eb1, const float* __restrict__ eb2,
    const float* __restrict__ dW, const float* __restrict__ db1, const float* __restrict__ db2,
    float* __restrict__ WTe, float* __restrict__ WTd,
    float* __restrict__ be, float* __restrict__ bd,
    unsigned long long* __restrict__ ex_all,   // [2 arrays][B][2][256] slots (fast+slow)
    unsigned* __restrict__ xcc_all)            // 512 handshake slots (in out buffer)
{
    int idx = blockIdx.x * 256 + threadIdx.x;
    if (idx < GD * HD) {
        int j = idx / HD, k = idx % HD;      // Whh[j][k]
        WTe[k * GD + j] = eW[idx];
        WTd[k * GD + j] = dW[idx];
    }
    if (idx < GD) {
        be[idx] = eb1[idx] + eb2[idx];
        bd[idx] = db1[idx] + db2[idx];
    }
    if (idx < 2 * BB * 2 * 256) ex_all[idx] = 0ULL;   // tags=0 (< any expected tag)
    if (idx < 512) xcc_all[idx] = 0u;                 // 0 = unset
}

// ---------------- LSTM scan: 4 blocks/chain, weights in VGPRs, tagged exchange ----------
// block = (b = blk&63, q = blk>>6); q owns hidden dims [64q, 64q+64)
// thread: s = tid&3 (k-quarter), jj = tid>>2 (row-pair 2jj,2jj+1 of block's 256 gate rows)
__global__ __launch_bounds__(NT, 2) void lstm_scan_coop(
    const float* __restrict__ x,       // [B,T]
    const float* __restrict__ Wih,     // [4H]
    const float* __restrict__ bias,    // [4H] (bih+bhh)
    const float* __restrict__ WT,      // [H][4H]
    const float* __restrict__ h_init,  // nullptr, or enc_states (reads [b][T-1][:])
    float* __restrict__ states,        // [B,T,H]
    unsigned long long* __restrict__ ex_fast,  // [B][2][256] sc0 slots (L2-local)
    unsigned long long* __restrict__ ex_slow,  // [B][2][256] agent slots (always valid)
    unsigned* __restrict__ xcc,        // [B][4] xcc-id handshake slots (zeroed)
    unsigned tag0)                     // 0 for encoder, 1024 for decoder
{
    const int b   = blockIdx.x & 63;
    const int q   = blockIdx.x >> 6;
    const int tid = threadIdx.x;
    const int s   = tid & 3;            // k-quarter
    const int jj  = tid >> 2;           // 0..127
    const int gate = jj >> 5;           // 0:i 1:f 2:g 3:o
    const int kk0  = (jj & 31) * 2;     // local dim pair
    const int r0   = gate * 64 + kk0;   // local row in [0,256)
    const int jg0  = gate * 256 + q * 64 + kk0;  // global gate row

    __shared__ float h_rep[4][264];
    __shared__ float act_s[256];
    __shared__ float x_s[TT];
    __shared__ int fast_sh;

    // ---- XCD co-location handshake (agent-scope, always correct; decides path) ----
    if (tid == 0) {
        // hwreg(id=20 XCC_ID, offset=0, size=4) -> imm16 = (4-1)<<11 | 0<<6 | 20 = 0x1814
        unsigned my = (__builtin_amdgcn_s_getreg(0x1814) & 0xFu) + 1u;  // 1..8, 0=unset
        __hip_atomic_store(&xcc[b * 4 + q], my, __ATOMIC_RELAXED, __HIP_MEMORY_SCOPE_AGENT);
        unsigned vv[4];
        #pragma unroll
        for (int i = 0; i < 4; ++i) {
            unsigned u;
            do {
                u = __hip_atomic_load(&xcc[b * 4 + i], __ATOMIC_RELAXED, __HIP_MEMORY_SCOPE_AGENT);
            } while (u == 0u);
            vv[i] = u;
        }
        fast_sh = (vv[0] == vv[1] && vv[1] == vv[2] && vv[2] == vv[3]) ? 1 : 0;
    }

    // ---- weights for rows jg0, jg0+1 over k in [64s,64s+64): 128 VGPRs ----
    float4 w0[16], w1[16];
    {
        const float* basek = WT + (size_t)(s * 64) * GD;
        #pragma unroll
        for (int i = 0; i < 16; ++i) {
            const float* p0 = basek + (size_t)(4 * i) * GD + jg0;
            w0[i] = make_float4(p0[0], p0[GD], p0[2 * GD], p0[3 * GD]);
            const float* p1 = p0 + 1;
            w1[i] = make_float4(p1[0], p1[GD], p1[2 * GD], p1[3 * GD]);
        }
    }
    const float wih0 = Wih[jg0], wih1 = Wih[jg0 + 1];
    const float bj0  = bias[jg0], bj1  = bias[jg0 + 1];

    for (int i = tid; i < TT; i += NT) x_s[i] = x[b * TT + i];
    if (tid < 256) {
        float hv = h_init ? h_init[((size_t)b * TT + (TT - 1)) * HD + tid] : 0.f;
        h_rep[tid >> 6][tid & 63] = hv;
    }
    float c = 0.f;   // live in wave q (tid in [64q,64q+64)) only
    __syncthreads();
    const int fast = fast_sh;   // wave-uniform

    for (int t = 0; t < TT; ++t) {
        // ---- gate pre-activation partial over this thread's k-quarter ----
        // split accumulators: halve the serial FMA dependency chain
        const float xt = x_s[t];
        float a0p, a1p, a0q = 0.f, a1q = 0.f;
        if (s == 0) { a0p = fmaf(xt, wih0, bj0); a1p = fmaf(xt, wih1, bj1); }
        else        { a0p = 0.f;                 a1p = 0.f; }
        const float4* h4 = (const float4*)(&h_rep[s][0]);
        #pragma unroll
        for (int i = 0; i < 8; ++i) {
            float4 hv = h4[i];
            a0p = fmaf(hv.x, w0[i].x, a0p); a0p = fmaf(hv.y, w0[i].y, a0p);
            a0p = fmaf(hv.z, w0[i].z, a0p); a0p = fmaf(hv.w, w0[i].w, a0p);
            a1p = fmaf(hv.x, w1[i].x, a1p); a1p = fmaf(hv.y, w1[i].y, a1p);
            a1p = fmaf(hv.z, w1[i].z, a1p); a1p = fmaf(hv.w, w1[i].w, a1p);
        }
        #pragma unroll
        for (int i = 8; i < 16; ++i) {
            float4 hv = h4[i];
            a0q = fmaf(hv.x, w0[i].x, a0q); a0q = fmaf(hv.y, w0[i].y, a0q);
            a0q = fmaf(hv.z, w0[i].z, a0q); a0q = fmaf(hv.w, w0[i].w, a0q);
            a1q = fmaf(hv.x, w1[i].x, a1q); a1q = fmaf(hv.y, w1[i].y, a1q);
            a1q = fmaf(hv.z, w1[i].z, a1q); a1q = fmaf(hv.w, w1[i].w, a1q);
        }
        float a0 = a0p + a0q;
        float a1 = a1p + a1q;
        a0 += __shfl_xor(a0, 1); a0 += __shfl_xor(a0, 2);
        a1 += __shfl_xor(a1, 1); a1 += __shfl_xor(a1, 2);
        if (s == 0) {
            float2 av;
            av.x = (gate == 2) ? tanh_(a0) : sig_(a0);
            av.y = (gate == 2) ? tanh_(a1) : sig_(a1);
            *(float2*)(&act_s[r0]) = av;
        }
        __syncthreads();   // act ready

        const unsigned tag = tag0 + (unsigned)t + 1u;
        unsigned long long* fsl = ex_fast + ((size_t)b * 2 + (t & 1)) * 256;
        unsigned long long* ssl = ex_slow + ((size_t)b * 2 + (t & 1)) * 256;
        if (tid < 256) {
            const int dq = tid >> 6, dk = tid & 63;
            if (dq == q) {
                float gi = act_s[dk], gf = act_s[64 + dk], gg = act_s[128 + dk], go = act_s[192 + dk];
                c = fmaf(gf, c, gi * gg);
                float h = go * tanh_(c);
                unsigned long long pk = ((unsigned long long)tag << 32)
                                      | (unsigned long long)__float_as_uint(h);
                // publish FIRST (earliest remote visibility); fast = write-through
                // to the XCD-shared L2 (sc0), slow = agent store (memory-side net)
                if (fast) {
                    unsigned long long* fp = fsl + tid;
                    asm volatile("global_store_dwordx2 %0, %1, off sc0"
                                 :: "v"(fp), "v"(pk) : "memory");
                }
                __hip_atomic_store(&ssl[tid], pk, __ATOMIC_RELAXED, __HIP_MEMORY_SCOPE_AGENT);
                h_rep[q][dk] = h;
                states[((size_t)(b * TT + t)) * HD + tid] = h;
            } else {
                unsigned long long u;
                bool ok = false;
                if (fast) {
                    const unsigned long long* fp = fsl + tid;
                    #pragma unroll 1
                    for (int it = 0; it < 400; ++it) {
                        asm volatile("global_load_dwordx2 %0, %1, off sc0\n\t"
                                     "s_waitcnt vmcnt(0)"
                                     : "=&v"(u) : "v"(fp) : "memory");
                        if ((unsigned)(u >> 32) == tag) { ok = true; break; }
                    }
                }
                if (!ok) {
                    do {
                        u = __hip_atomic_load(&ssl[tid], __ATOMIC_RELAXED, __HIP_MEMORY_SCOPE_AGENT);
                    } while ((unsigned)(u >> 32) != tag);
                }
                h_rep[dq][dk] = __uint_as_float((unsigned)u);
            }
        }
        __syncthreads();   // h replicas ready for t+1
    }
}

// ---------------- proj: ew[b][t]=E·w1, hw[b][t]=Hx·w2 (one wave per row) ----------------
__global__ __launch_bounds__(256) void proj_kernel(
    const float* __restrict__ enc_states, const float* __restrict__ dec_hs,
    const float* __restrict__ linW, float* __restrict__ ew, float* __restrict__ hw)
{
    const int lane = threadIdx.x & 63;
    const int wid  = blockIdx.x * 4 + (threadIdx.x >> 6);
    const int nw   = gridDim.x * 4;
    const float4 w1 = ((const float4*)linW)[lane];
    const float4 w2 = ((const float4*)(linW + HD))[lane];
    for (int o = wid; o < BB * TT; o += nw) {
        float4 v1 = ((const float4*)(enc_states + (size_t)o * HD))[lane];
        float4 v2 = ((const float4*)(dec_hs     + (size_t)o * HD))[lane];
        float s1 = v1.x * w1.x + v1.y * w1.y + v1.z * w1.z + v1.w * w1.w;
        float s2 = v2.x * w2.x + v2.y * w2.y + v2.z * w2.z + v2.w * w2.w;
        #pragma unroll
        for (int m = 1; m < 64; m <<= 1) {
            s1 += __shfl_xor(s1, m);
            s2 += __shfl_xor(s2, m);
        }
        if (lane == 0) { ew[o] = s1; hw[o] = s2; }
    }
}

// ---------------- attention v2: 32 td rows/block, 4x8 register tile ----------------
// Hx[k][td] stride 36 (16B-aligned rows): per k one wave-uniform ds_read_b128
// E[k][te]: lane-consecutive b32 reads (conflict-free, broadcast across td groups)
#define TD2  32    // td rows per block
#define TEC2 256   // te chunk
#define KC2  32    // k chunk
__global__ __launch_bounds__(256) void attn_kernel(
    const float* __restrict__ enc_states,  // [B][T][H]
    const float* __restrict__ dec_hs,      // [B][T][H]
    const float* __restrict__ ew, const float* __restrict__ hw,
    const float* __restrict__ lin_b,
    float* __restrict__ out)               // [B][T]
{
    const int b   = blockIdx.y;
    const int td0 = blockIdx.x * TD2;
    const int tid = threadIdx.x;
    const int tdt = tid >> 5;   // 0..7 (4 td rows each)
    const int tet = tid & 31;   // 0..31

    __shared__ float Hx[HD][TD2 + 4];   // stride 36: rows 16B-aligned
    __shared__ float E[KC2][TEC2];

    // stage Hx: thread -> (td = tid>>3, 32-k chunk = (tid&7)*32)
    {
        const int td = tid >> 3;
        const int kc = (tid & 7) * 32;
        const float* src = dec_hs + ((size_t)b * TT + td0 + td) * HD + kc;
        #pragma unroll
        for (int qq = 0; qq < 8; ++qq) {
            float4 v = ((const float4*)(src + qq * 4))[0];
            Hx[kc + qq * 4 + 0][td] = v.x;
            Hx[kc + qq * 4 + 1][td] = v.y;
            Hx[kc + qq * 4 + 2][td] = v.z;
            Hx[kc + qq * 4 + 3][td] = v.w;
        }
    }

    float M[4]  = {-1e30f, -1e30f, -1e30f, -1e30f};
    float Nm[4] = {0.f, 0.f, 0.f, 0.f};
    float Dn[4] = {0.f, 0.f, 0.f, 0.f};

    for (int tc = 0; tc < TT / TEC2; ++tc) {
        const int te0 = tc * TEC2;
        float S[4][8] = {{0.f}};
        for (int kc = 0; kc < HD / KC2; ++kc) {
            const int k0 = kc * KC2;
            __syncthreads();
            {   // stage E chunk: thread = te row, 32 consecutive k
                const float* src = enc_states + ((size_t)b * TT + te0 + tid) * HD + k0;
                #pragma unroll
                for (int qq = 0; qq < 8; ++qq) {
                    float4 v = ((const float4*)(src + qq * 4))[0];
                    E[qq * 4 + 0][tid] = v.x;
                    E[qq * 4 + 1][tid] = v.y;
                    E[qq * 4 + 2][tid] = v.z;
                    E[qq * 4 + 3][tid] = v.w;
                }
            }
            __syncthreads();
            #pragma unroll 4
            for (int k = 0; k < KC2; ++k) {
                const float4 hx4 = *(const float4*)(&Hx[k0 + k][tdt * 4]);
                #pragma unroll
                for (int i = 0; i < 8; ++i) {
                    const float e = E[k][tet + 32 * i];
                    S[0][i] = fmaf(hx4.x, e, S[0][i]);
                    S[1][i] = fmaf(hx4.y, e, S[1][i]);
                    S[2][i] = fmaf(hx4.z, e, S[2][i]);
                    S[3][i] = fmaf(hx4.w, e, S[3][i]);
                }
            }
        }
        float ewv[8];
        #pragma unroll
        for (int i = 0; i < 8; ++i) ewv[i] = ew[(size_t)b * TT + te0 + tet + 32 * i];
        #pragma unroll
        for (int r = 0; r < 4; ++r) {
            float cm = S[r][0];
            #pragma unroll
            for (int i = 1; i < 8; ++i) cm = fmaxf(cm, S[r][i]);
            #pragma unroll
            for (int m = 1; m < 32; m <<= 1) cm = fmaxf(cm, __shfl_xor(cm, m));
            const float newM  = fmaxf(M[r], cm);
            const float scale = __expf(M[r] - newM);
            float nl = 0.f, dl = 0.f;
            #pragma unroll
            for (int i = 0; i < 8; ++i) {
                const float p = __expf(S[r][i] - newM);
                dl += p;
                nl = fmaf(p, ewv[i], nl);
            }
            #pragma unroll
            for (int m = 1; m < 32; m <<= 1) {
                nl += __shfl_xor(nl, m);
                dl += __shfl_xor(dl, m);
            }
            Nm[r] = Nm[r] * scale + nl;
            Dn[r] = Dn[r] * scale + dl;
            M[r]  = newM;
        }
    }

    if (tet == 0) {
        const float lb = lin_b[0];
        #pragma unroll
        for (int r = 0; r < 4; ++r) {
            const int td = td0 + tdt * 4 + r;
            out[(size_t)b * TT + td] = Nm[r] / Dn[r] + hw[(size_t)b * TT + td] + lb;
        }
    }
}

extern "C" void kernel_launch(void* const* d_in, const int* in_sizes, int n_in,
                              void* d_out, int out_size, void* d_ws, size_t ws_size,
                              hipStream_t stream)
{
    const float* x    = (const float*)d_in[0];
    const float* eWih = (const float*)d_in[1];
    const float* eWhh = (const float*)d_in[2];
    const float* ebih = (const float*)d_in[3];
    const float* ebhh = (const float*)d_in[4];
    const float* dWih = (const float*)d_in[5];
    const float* dWhh = (const float*)d_in[6];
    const float* dbih = (const float*)d_in[7];
    const float* dbhh = (const float*)d_in[8];
    const float* linW = (const float*)d_in[9];
    const float* linb = (const float*)d_in[10];
    float* out = (float*)d_out;

    // ws layout: byte-identical to R4
    float* p = (float*)d_ws;
    float* WTe = p;        p += (size_t)GD * HD;
    float* WTd = p;        p += (size_t)GD * HD;
    float* be  = p;        p += GD;
    float* bd  = p;        p += GD;
    float* enc_states = p; p += (size_t)BB * TT * HD;
    float* dec_hs = p;     p += (size_t)BB * TT * HD;
    float* ew = p;         p += (size_t)BB * TT;
    float* hw = p;         p += (size_t)BB * TT;
    unsigned long long* ex_fast = (unsigned long long*)p; p += (size_t)BB * 2 * 256 * 2;
    unsigned long long* ex_slow = (unsigned long long*)p; p += (size_t)BB * 2 * 256 * 2;
    // handshake slots live in out[0:512] (scratch; attn fully overwrites out)
    unsigned* xcc_e = (unsigned*)out;
    unsigned* xcc_d = xcc_e + 256;

    prep_kernel<<<(GD * HD + 255) / 256, 256, 0, stream>>>(
        eWhh, ebih, ebhh, dWhh, dbih, dbhh, WTe, WTd, be, bd,
        ex_fast, (unsigned*)out);

    unsigned tag0e = 0u, tag0d = 1024u;
    {
        const float* hi = nullptr;
        void* args[] = {(void*)&x, (void*)&eWih, (void*)&be, (void*)&WTe,
                        (void*)&hi, (void*)&enc_states, (void*)&ex_fast,
                        (void*)&ex_slow, (void*)&xcc_e, (void*)&tag0e};
        hipLaunchCooperativeKernel((void*)lstm_scan_coop, dim3(256), dim3(NT),
                                   args, 0, stream);
    }
    {
        const float* hi = enc_states;
        void* args[] = {(void*)&x, (void*)&dWih, (void*)&bd, (void*)&WTd,
                        (void*)&hi, (void*)&dec_hs, (void*)&ex_fast,
                        (void*)&ex_slow, (void*)&xcc_d, (void*)&tag0d};
        hipLaunchCooperativeKernel((void*)lstm_scan_coop, dim3(256), dim3(NT),
                                   args, 0, stream);
    }

    proj_kernel<<<256, 256, 0, stream>>>(enc_states, dec_hs, linW, ew, hw);
    attn_kernel<<<dim3(TT / TD2, BB), 256, 0, stream>>>(enc_states, dec_hs, ew, hw, linb, out);
}

// Round 3
// 4320.487 us; speedup vs baseline: 17.2845x; 17.2845x over previous
//
// Encoder-decoder LSTM + dot attention + linear, MI355X fp32.  R7
// R6 post-mortem: xcc-handshake said "fast" but sc0 visibility was absent ->
// 400 wasted spins/step -> 60ms scans (VALUBusy 4.5%). Lesson: never infer
// co-location from a hwreg read; TEST the mechanism.
// R7: one-time empirical visibility probe (plain store -> sc0 poll, bounded;
// unanimous AND via agent path) gates the fast exchange. Per-step: always
// dual-publish (plain store to fast slot + agent store to slow slot); fast
// poll bounded 3000 spins with STICKY fallback (one timeout max, ~200us).
// Probe pass  -> scans ~900-1150us each, FETCH 103->~20MB, total ~2600us.
// Probe fail  -> exact R4 behavior (~3950us), lever falsified.
#include <hip/hip_runtime.h>
#include <math.h>

#define HD 256
#define GD 1024   // 4*H
#define TT 1024
#define BB 64
#define NT 512    // scan block size
#define PROBE_SPINS 5000
#define STEP_SPINS  3000

__device__ __forceinline__ float sig_(float x)  { return 1.f / (1.f + __expf(-x)); }
__device__ __forceinline__ float tanh_(float x) { return 1.f - 2.f / (1.f + __expf(2.f * x)); }

// ---------------- prep: transpose Whh -> [k][j], bias sums, zero exchange ----------------
__global__ __launch_bounds__(256) void prep_kernel(
    const float* __restrict__ eW, const float* __restrict__ eb1, const float* __restrict__ eb2,
    const float* __restrict__ dW, const float* __restrict__ db1, const float* __restrict__ db2,
    float* __restrict__ WTe, float* __restrict__ WTd,
    float* __restrict__ be, float* __restrict__ bd,
    unsigned long long* __restrict__ ex_all,   // [2 arrays][B][2][256] slots (fast+slow)
    unsigned* __restrict__ probe_all)          // 1024 u32: pf_e, pf_d, ok_e, ok_d (in out buffer)
{
    int idx = blockIdx.x * 256 + threadIdx.x;
    if (idx < GD * HD) {
        int j = idx / HD, k = idx % HD;      // Whh[j][k]
        WTe[k * GD + j] = eW[idx];
        WTd[k * GD + j] = dW[idx];
    }
    if (idx < GD) {
        be[idx] = eb1[idx] + eb2[idx];
        bd[idx] = db1[idx] + db2[idx];
    }
    if (idx < 2 * BB * 2 * 256) ex_all[idx] = 0ULL;   // tags=0 (< any expected tag)
    if (idx < 1024) probe_all[idx] = 0u;              // probe + ok slots
}

// ---------------- LSTM scan: 4 blocks/chain, weights in VGPRs, tagged exchange ----------
// block = (b = blk&63, q = blk>>6); q owns hidden dims [64q, 64q+64)
// thread: s = tid&3 (k-quarter), jj = tid>>2 (row-pair 2jj,2jj+1 of block's 256 gate rows)
__global__ __launch_bounds__(NT, 2) void lstm_scan_coop(
    const float* __restrict__ x,       // [B,T]
    const float* __restrict__ Wih,     // [4H]
    const float* __restrict__ bias,    // [4H] (bih+bhh)
    const float* __restrict__ WT,      // [H][4H]
    const float* __restrict__ h_init,  // nullptr, or enc_states (reads [b][T-1][:])
    float* __restrict__ states,        // [B,T,H]
    unsigned long long* __restrict__ ex_fast,  // [B][2][256] plain-store slots (L2-local if co-XCD)
    unsigned long long* __restrict__ ex_slow,  // [B][2][256] agent slots (always valid)
    unsigned* __restrict__ pf,         // [B][4] probe words (zeroed)
    unsigned* __restrict__ okv,        // [B][4] ok slots (zeroed)
    unsigned tag0)                     // 0 for encoder, 1024 for decoder
{
    const int b   = blockIdx.x & 63;
    const int q   = blockIdx.x >> 6;
    const int tid = threadIdx.x;
    const int s   = tid & 3;            // k-quarter
    const int jj  = tid >> 2;           // 0..127
    const int gate = jj >> 5;           // 0:i 1:f 2:g 3:o
    const int kk0  = (jj & 31) * 2;     // local dim pair
    const int r0   = gate * 64 + kk0;   // local row in [0,256)
    const int jg0  = gate * 256 + q * 64 + kk0;  // global gate row

    __shared__ float h_rep[4][264];
    __shared__ float act_s[256];
    __shared__ float x_s[TT];
    __shared__ int fast_sh;

    // ---- one-time EMPIRICAL visibility probe (tid 0; overlaps others' weight loads) ----
    // Tests the actual fast-path instructions on the actual placement. Unanimous AND
    // via the always-correct agent path decides the per-step exchange mode.
    if (tid == 0) {
        unsigned pv = 0xA5000000u | (unsigned)(q + 1);
        unsigned* fp = pf + b * 4 + q;
        asm volatile("global_store_dword %0, %1, off" :: "v"(fp), "v"(pv) : "memory");
        int okall = 1;
        #pragma unroll 1
        for (int i = 0; i < 4; ++i) {
            if (i == q) continue;
            const unsigned* pp = pf + b * 4 + i;
            const unsigned expect = 0xA5000000u | (unsigned)(i + 1);
            int got = 0;
            #pragma unroll 1
            for (int it = 0; it < PROBE_SPINS; ++it) {
                unsigned u;
                asm volatile("global_load_dword %0, %1, off sc0\n\ts_waitcnt vmcnt(0)"
                             : "=&v"(u) : "v"(pp) : "memory");
                if (u == expect) { got = 1; break; }
            }
            okall &= got;
        }
        __hip_atomic_store(&okv[b * 4 + q], 0x100u | (unsigned)okall,
                           __ATOMIC_RELAXED, __HIP_MEMORY_SCOPE_AGENT);
        int f = 1;
        #pragma unroll 1
        for (int i = 0; i < 4; ++i) {
            unsigned u;
            do {
                u = __hip_atomic_load(&okv[b * 4 + i], __ATOMIC_RELAXED, __HIP_MEMORY_SCOPE_AGENT);
            } while (!(u & 0x100u));
            f &= (int)(u & 1u);
        }
        fast_sh = f;
    }

    // ---- weights for rows jg0, jg0+1 over k in [64s,64s+64): 128 VGPRs ----
    float4 w0[16], w1[16];
    {
        const float* basek = WT + (size_t)(s * 64) * GD;
        #pragma unroll
        for (int i = 0; i < 16; ++i) {
            const float* p0 = basek + (size_t)(4 * i) * GD + jg0;
            w0[i] = make_float4(p0[0], p0[GD], p0[2 * GD], p0[3 * GD]);
            const float* p1 = p0 + 1;
            w1[i] = make_float4(p1[0], p1[GD], p1[2 * GD], p1[3 * GD]);
        }
    }
    const float wih0 = Wih[jg0], wih1 = Wih[jg0 + 1];
    const float bj0  = bias[jg0], bj1  = bias[jg0 + 1];

    for (int i = tid; i < TT; i += NT) x_s[i] = x[b * TT + i];
    if (tid < 256) {
        float hv = h_init ? h_init[((size_t)b * TT + (TT - 1)) * HD + tid] : 0.f;
        h_rep[tid >> 6][tid & 63] = hv;
    }
    float c = 0.f;   // live in wave q (tid in [64q,64q+64)) only
    __syncthreads();

    for (int t = 0; t < TT; ++t) {
        // ---- gate pre-activation partial over this thread's k-quarter ----
        // split accumulators: halve the serial FMA dependency chain
        const float xt = x_s[t];
        float a0p, a1p, a0q = 0.f, a1q = 0.f;
        if (s == 0) { a0p = fmaf(xt, wih0, bj0); a1p = fmaf(xt, wih1, bj1); }
        else        { a0p = 0.f;                 a1p = 0.f; }
        const float4* h4 = (const float4*)(&h_rep[s][0]);
        #pragma unroll
        for (int i = 0; i < 8; ++i) {
            float4 hv = h4[i];
            a0p = fmaf(hv.x, w0[i].x, a0p); a0p = fmaf(hv.y, w0[i].y, a0p);
            a0p = fmaf(hv.z, w0[i].z, a0p); a0p = fmaf(hv.w, w0[i].w, a0p);
            a1p = fmaf(hv.x, w1[i].x, a1p); a1p = fmaf(hv.y, w1[i].y, a1p);
            a1p = fmaf(hv.z, w1[i].z, a1p); a1p = fmaf(hv.w, w1[i].w, a1p);
        }
        #pragma unroll
        for (int i = 8; i < 16; ++i) {
            float4 hv = h4[i];
            a0q = fmaf(hv.x, w0[i].x, a0q); a0q = fmaf(hv.y, w0[i].y, a0q);
            a0q = fmaf(hv.z, w0[i].z, a0q); a0q = fmaf(hv.w, w0[i].w, a0q);
            a1q = fmaf(hv.x, w1[i].x, a1q); a1q = fmaf(hv.y, w1[i].y, a1q);
            a1q = fmaf(hv.z, w1[i].z, a1q); a1q = fmaf(hv.w, w1[i].w, a1q);
        }
        float a0 = a0p + a0q;
        float a1 = a1p + a1q;
        a0 += __shfl_xor(a0, 1); a0 += __shfl_xor(a0, 2);
        a1 += __shfl_xor(a1, 1); a1 += __shfl_xor(a1, 2);
        if (s == 0) {
            float2 av;
            av.x = (gate == 2) ? tanh_(a0) : sig_(a0);
            av.y = (gate == 2) ? tanh_(a1) : sig_(a1);
            *(float2*)(&act_s[r0]) = av;
        }
        __syncthreads();   // act ready (also orders fast_sh sticky writes)

        const unsigned tag = tag0 + (unsigned)t + 1u;
        unsigned long long* fsl = ex_fast + ((size_t)b * 2 + (t & 1)) * 256;
        unsigned long long* ssl = ex_slow + ((size_t)b * 2 + (t & 1)) * 256;
        if (tid < 256) {
            const int dq = tid >> 6, dk = tid & 63;   // wave-uniform dq
            if (dq == q) {
                float gi = act_s[dk], gf = act_s[64 + dk], gg = act_s[128 + dk], go = act_s[192 + dk];
                c = fmaf(gf, c, gi * gg);
                float h = go * tanh_(c);
                unsigned long long pk = ((unsigned long long)tag << 32)
                                      | (unsigned long long)__float_as_uint(h);
                // dual publish, fast first: plain store drains write-through L1 -> L2
                {
                    unsigned long long* fp2 = fsl + tid;
                    asm volatile("global_store_dwordx2 %0, %1, off"
                                 :: "v"(fp2), "v"(pk) : "memory");
                }
                __hip_atomic_store(&ssl[tid], pk, __ATOMIC_RELAXED, __HIP_MEMORY_SCOPE_AGENT);
                h_rep[q][dk] = h;
                states[((size_t)(b * TT + t)) * HD + tid] = h;
            } else {
                unsigned long long u;
                int got = 0;
                if (fast_sh) {
                    const unsigned long long* fp2 = fsl + tid;
                    #pragma unroll 1
                    for (int it = 0; it < STEP_SPINS; ++it) {
                        asm volatile("global_load_dwordx2 %0, %1, off sc0\n\ts_waitcnt vmcnt(0)"
                                     : "=&v"(u) : "v"(fp2) : "memory");
                        if ((unsigned)(u >> 32) == tag) { got = 1; break; }
                    }
                    if (!got) fast_sh = 0;   // sticky fallback: at most ONE timeout total
                }
                if (!got) {
                    do {
                        u = __hip_atomic_load(&ssl[tid], __ATOMIC_RELAXED, __HIP_MEMORY_SCOPE_AGENT);
                    } while ((unsigned)(u >> 32) != tag);
                }
                h_rep[dq][dk] = __uint_as_float((unsigned)u);
            }
        }
        __syncthreads();   // h replicas ready for t+1
    }
}

// ---------------- proj: ew[b][t]=E·w1, hw[b][t]=Hx·w2 (one wave per row) ----------------
__global__ __launch_bounds__(256) void proj_kernel(
    const float* __restrict__ enc_states, const float* __restrict__ dec_hs,
    const float* __restrict__ linW, float* __restrict__ ew, float* __restrict__ hw)
{
    const int lane = threadIdx.x & 63;
    const int wid  = blockIdx.x * 4 + (threadIdx.x >> 6);
    const int nw   = gridDim.x * 4;
    const float4 w1 = ((const float4*)linW)[lane];
    const float4 w2 = ((const float4*)(linW + HD))[lane];
    for (int o = wid; o < BB * TT; o += nw) {
        float4 v1 = ((const float4*)(enc_states + (size_t)o * HD))[lane];
        float4 v2 = ((const float4*)(dec_hs     + (size_t)o * HD))[lane];
        float s1 = v1.x * w1.x + v1.y * w1.y + v1.z * w1.z + v1.w * w1.w;
        float s2 = v2.x * w2.x + v2.y * w2.y + v2.z * w2.z + v2.w * w2.w;
        #pragma unroll
        for (int m = 1; m < 64; m <<= 1) {
            s1 += __shfl_xor(s1, m);
            s2 += __shfl_xor(s2, m);
        }
        if (lane == 0) { ew[o] = s1; hw[o] = s2; }
    }
}

// ---------------- attention v2: 32 td rows/block, 4x8 register tile ----------------
// Hx[k][td] stride 36 (16B-aligned rows): per k one wave-uniform ds_read_b128
// E[k][te]: lane-consecutive b32 reads (conflict-free, broadcast across td groups)
#define TD2  32    // td rows per block
#define TEC2 256   // te chunk
#define KC2  32    // k chunk
__global__ __launch_bounds__(256) void attn_kernel(
    const float* __restrict__ enc_states,  // [B][T][H]
    const float* __restrict__ dec_hs,      // [B][T][H]
    const float* __restrict__ ew, const float* __restrict__ hw,
    const float* __restrict__ lin_b,
    float* __restrict__ out)               // [B][T]
{
    const int b   = blockIdx.y;
    const int td0 = blockIdx.x * TD2;
    const int tid = threadIdx.x;
    const int tdt = tid >> 5;   // 0..7 (4 td rows each)
    const int tet = tid & 31;   // 0..31

    __shared__ float Hx[HD][TD2 + 4];   // stride 36: rows 16B-aligned
    __shared__ float E[KC2][TEC2];

    // stage Hx: thread -> (td = tid>>3, 32-k chunk = (tid&7)*32)
    {
        const int td = tid >> 3;
        const int kc = (tid & 7) * 32;
        const float* src = dec_hs + ((size_t)b * TT + td0 + td) * HD + kc;
        #pragma unroll
        for (int qq = 0; qq < 8; ++qq) {
            float4 v = ((const float4*)(src + qq * 4))[0];
            Hx[kc + qq * 4 + 0][td] = v.x;
            Hx[kc + qq * 4 + 1][td] = v.y;
            Hx[kc + qq * 4 + 2][td] = v.z;
            Hx[kc + qq * 4 + 3][td] = v.w;
        }
    }

    float M[4]  = {-1e30f, -1e30f, -1e30f, -1e30f};
    float Nm[4] = {0.f, 0.f, 0.f, 0.f};
    float Dn[4] = {0.f, 0.f, 0.f, 0.f};

    for (int tc = 0; tc < TT / TEC2; ++tc) {
        const int te0 = tc * TEC2;
        float S[4][8] = {{0.f}};
        for (int kc = 0; kc < HD / KC2; ++kc) {
            const int k0 = kc * KC2;
            __syncthreads();
            {   // stage E chunk: thread = te row, 32 consecutive k
                const float* src = enc_states + ((size_t)b * TT + te0 + tid) * HD + k0;
                #pragma unroll
                for (int qq = 0; qq < 8; ++qq) {
                    float4 v = ((const float4*)(src + qq * 4))[0];
                    E[qq * 4 + 0][tid] = v.x;
                    E[qq * 4 + 1][tid] = v.y;
                    E[qq * 4 + 2][tid] = v.z;
                    E[qq * 4 + 3][tid] = v.w;
                }
            }
            __syncthreads();
            #pragma unroll 4
            for (int k = 0; k < KC2; ++k) {
                const float4 hx4 = *(const float4*)(&Hx[k0 + k][tdt * 4]);
                #pragma unroll
                for (int i = 0; i < 8; ++i) {
                    const float e = E[k][tet + 32 * i];
                    S[0][i] = fmaf(hx4.x, e, S[0][i]);
                    S[1][i] = fmaf(hx4.y, e, S[1][i]);
                    S[2][i] = fmaf(hx4.z, e, S[2][i]);
                    S[3][i] = fmaf(hx4.w, e, S[3][i]);
                }
            }
        }
        float ewv[8];
        #pragma unroll
        for (int i = 0; i < 8; ++i) ewv[i] = ew[(size_t)b * TT + te0 + tet + 32 * i];
        #pragma unroll
        for (int r = 0; r < 4; ++r) {
            float cm = S[r][0];
            #pragma unroll
            for (int i = 1; i < 8; ++i) cm = fmaxf(cm, S[r][i]);
            #pragma unroll
            for (int m = 1; m < 32; m <<= 1) cm = fmaxf(cm, __shfl_xor(cm, m));
            const float newM  = fmaxf(M[r], cm);
            const float scale = __expf(M[r] - newM);
            float nl = 0.f, dl = 0.f;
            #pragma unroll
            for (int i = 0; i < 8; ++i) {
                const float p = __expf(S[r][i] - newM);
                dl += p;
                nl = fmaf(p, ewv[i], nl);
            }
            #pragma unroll
            for (int m = 1; m < 32; m <<= 1) {
                nl += __shfl_xor(nl, m);
                dl += __shfl_xor(dl, m);
            }
            Nm[r] = Nm[r] * scale + nl;
            Dn[r] = Dn[r] * scale + dl;
            M[r]  = newM;
        }
    }

    if (tet == 0) {
        const float lb = lin_b[0];
        #pragma unroll
        for (int r = 0; r < 4; ++r) {
            const int td = td0 + tdt * 4 + r;
            out[(size_t)b * TT + td] = Nm[r] / Dn[r] + hw[(size_t)b * TT + td] + lb;
        }
    }
}

extern "C" void kernel_launch(void* const* d_in, const int* in_sizes, int n_in,
                              void* d_out, int out_size, void* d_ws, size_t ws_size,
                              hipStream_t stream)
{
    const float* x    = (const float*)d_in[0];
    const float* eWih = (const float*)d_in[1];
    const float* eWhh = (const float*)d_in[2];
    const float* ebih = (const float*)d_in[3];
    const float* ebhh = (const float*)d_in[4];
    const float* dWih = (const float*)d_in[5];
    const float* dWhh = (const float*)d_in[6];
    const float* dbih = (const float*)d_in[7];
    const float* dbhh = (const float*)d_in[8];
    const float* linW = (const float*)d_in[9];
    const float* linb = (const float*)d_in[10];
    float* out = (float*)d_out;

    // ws layout: byte-identical to R4
    float* p = (float*)d_ws;
    float* WTe = p;        p += (size_t)GD * HD;
    float* WTd = p;        p += (size_t)GD * HD;
    float* be  = p;        p += GD;
    float* bd  = p;        p += GD;
    float* enc_states = p; p += (size_t)BB * TT * HD;
    float* dec_hs = p;     p += (size_t)BB * TT * HD;
    float* ew = p;         p += (size_t)BB * TT;
    float* hw = p;         p += (size_t)BB * TT;
    unsigned long long* ex_fast = (unsigned long long*)p; p += (size_t)BB * 2 * 256 * 2;
    unsigned long long* ex_slow = (unsigned long long*)p; p += (size_t)BB * 2 * 256 * 2;
    // probe + ok slots live in out[0:1024] (scratch; attn fully overwrites out)
    unsigned* pf_e = (unsigned*)out;       // 256
    unsigned* pf_d = pf_e + 256;           // 256
    unsigned* ok_e = pf_e + 512;           // 256
    unsigned* ok_d = pf_e + 768;           // 256

    prep_kernel<<<(GD * HD + 255) / 256, 256, 0, stream>>>(
        eWhh, ebih, ebhh, dWhh, dbih, dbhh, WTe, WTd, be, bd,
        ex_fast, (unsigned*)out);

    unsigned tag0e = 0u, tag0d = 1024u;
    {
        const float* hi = nullptr;
        void* args[] = {(void*)&x, (void*)&eWih, (void*)&be, (void*)&WTe,
                        (void*)&hi, (void*)&enc_states, (void*)&ex_fast,
                        (void*)&ex_slow, (void*)&pf_e, (void*)&ok_e, (void*)&tag0e};
        hipLaunchCooperativeKernel((void*)lstm_scan_coop, dim3(256), dim3(NT),
                                   args, 0, stream);
    }
    {
        const float* hi = enc_states;
        void* args[] = {(void*)&x, (void*)&dWih, (void*)&bd, (void*)&WTd,
                        (void*)&hi, (void*)&dec_hs, (void*)&ex_fast,
                        (void*)&ex_slow, (void*)&pf_d, (void*)&ok_d, (void*)&tag0d};
        hipLaunchCooperativeKernel((void*)lstm_scan_coop, dim3(256), dim3(NT),
                                   args, 0, stream);
    }

    proj_kernel<<<256, 256, 0, stream>>>(enc_states, dec_hs, linW, ew, hw);
    attn_kernel<<<dim3(TT / TD2, BB), 256, 0, stream>>>(enc_states, dec_hs, ew, hw, linb, out);
}

// Round 4
// 4082.200 us; speedup vs baseline: 18.2934x; 1.0584x over previous
//
// Encoder-decoder LSTM + dot attention + linear, MI355X fp32.  R8
// R7 post-mortem: probe failed (scans 1864us = R4 + probe cost; FETCH ~same).
// WRITE unchanged despite dual-publish => plain fast-stores ARE absorbed by L2;
// so the failure is placement: chain blocks {b,b+64,b+128,b+192} are NOT
// co-XCD => round-robin dispatch assumption wrong; chunked (32 blocks/XCD)
// placement would explain it and makes {4b..4b+3} co-XCD instead.
// R8 A/B in one bench: both scans NORMAL launch (capacity guarantees
// co-residency); encoder uses rr mapping (b=blk&63,q=blk>>6), decoder uses
// chunked mapping (b=blk>>2,q=blk&3). Parallel probe (lanes 0-3), 600 spins;
// step spins 1200, sticky fallback.
// Pred: chunked real -> dec scan 700-1000us / enc ~1650 (or mirrored);
// neither -> both ~1650, mechanism falsified.
#include <hip/hip_runtime.h>
#include <math.h>

#define HD 256
#define GD 1024   // 4*H
#define TT 1024
#define BB 64
#define NT 512    // scan block size
#define PROBE_SPINS 600
#define STEP_SPINS  1200

__device__ __forceinline__ float sig_(float x)  { return 1.f / (1.f + __expf(-x)); }
__device__ __forceinline__ float tanh_(float x) { return 1.f - 2.f / (1.f + __expf(2.f * x)); }

// ---------------- prep: transpose Whh -> [k][j], bias sums, zero exchange ----------------
__global__ __launch_bounds__(256) void prep_kernel(
    const float* __restrict__ eW, const float* __restrict__ eb1, const float* __restrict__ eb2,
    const float* __restrict__ dW, const float* __restrict__ db1, const float* __restrict__ db2,
    float* __restrict__ WTe, float* __restrict__ WTd,
    float* __restrict__ be, float* __restrict__ bd,
    unsigned long long* __restrict__ ex_all,   // [2 arrays][B][2][256] slots (fast+slow)
    unsigned* __restrict__ probe_all)          // 1024 u32: pf_e, ok_e, pf_d, ok_d (in out buffer)
{
    int idx = blockIdx.x * 256 + threadIdx.x;
    if (idx < GD * HD) {
        int j = idx / HD, k = idx % HD;      // Whh[j][k]
        WTe[k * GD + j] = eW[idx];
        WTd[k * GD + j] = dW[idx];
    }
    if (idx < GD) {
        be[idx] = eb1[idx] + eb2[idx];
        bd[idx] = db1[idx] + db2[idx];
    }
    if (idx < 2 * BB * 2 * 256) ex_all[idx] = 0ULL;   // tags=0 (< any expected tag)
    if (idx < 1024) probe_all[idx] = 0u;              // probe + ok slots
}

// ---------------- LSTM scan: 4 blocks/chain, weights in VGPRs, tagged exchange ----------
// mapping: chunked=0 -> b=blk&63, q=blk>>6 (co-XCD iff round-robin dispatch)
//          chunked=1 -> b=blk>>2, q=blk&3  (co-XCD iff chunked dispatch)
// thread: s = tid&3 (k-quarter), jj = tid>>2 (row-pair 2jj,2jj+1 of block's 256 gate rows)
__global__ __launch_bounds__(NT, 2) void lstm_scan_coop(
    const float* __restrict__ x,       // [B,T]
    const float* __restrict__ Wih,     // [4H]
    const float* __restrict__ bias,    // [4H] (bih+bhh)
    const float* __restrict__ WT,      // [H][4H]
    const float* __restrict__ h_init,  // nullptr, or enc_states (reads [b][T-1][:])
    float* __restrict__ states,        // [B,T,H]
    unsigned long long* __restrict__ ex_fast,  // [B][2][256] plain-store slots (L2-local if co-XCD)
    unsigned long long* __restrict__ ex_slow,  // [B][2][256] agent slots (always valid)
    unsigned* __restrict__ pf,         // [B][4] probe words (zeroed)
    unsigned* __restrict__ okv,        // [B][4] ok slots (zeroed)
    unsigned tag0,                     // 0 for encoder, 1024 for decoder
    int chunked)
{
    const int b   = chunked ? ((int)blockIdx.x >> 2) : ((int)blockIdx.x & 63);
    const int q   = chunked ? ((int)blockIdx.x & 3)  : ((int)blockIdx.x >> 6);
    const int tid = threadIdx.x;
    const int s   = tid & 3;            // k-quarter
    const int jj  = tid >> 2;           // 0..127
    const int gate = jj >> 5;           // 0:i 1:f 2:g 3:o
    const int kk0  = (jj & 31) * 2;     // local dim pair
    const int r0   = gate * 64 + kk0;   // local row in [0,256)
    const int jg0  = gate * 256 + q * 64 + kk0;  // global gate row

    __shared__ float h_rep[4][264];
    __shared__ float act_s[256];
    __shared__ float x_s[TT];
    __shared__ int fast_sh;

    // ---- one-time EMPIRICAL visibility probe (lanes 0..3 in parallel) ----
    // Tests the actual fast-path instructions on the actual placement. Unanimous AND
    // via the always-correct agent path decides the per-step exchange mode.
    if (tid < 4) {
        if (tid == q) {
            unsigned* fp = pf + b * 4 + q;
            unsigned pv = 0xA5000000u | (unsigned)(q + 1);
            asm volatile("global_store_dword %0, %1, off" :: "v"(fp), "v"(pv) : "memory");
        }
        int ok = 1;
        if (tid != q) {
            const unsigned* pp = pf + b * 4 + tid;
            const unsigned expect = 0xA5000000u | (unsigned)(tid + 1);
            ok = 0;
            #pragma unroll 1
            for (int it = 0; it < PROBE_SPINS; ++it) {
                unsigned u;
                asm volatile("global_load_dword %0, %1, off sc0\n\ts_waitcnt vmcnt(0)"
                             : "=&v"(u) : "v"(pp) : "memory");
                if (u == expect) { ok = 1; break; }
            }
        }
        unsigned long long m = __ballot(ok != 0);
        if (tid == 0) {
            int okall = ((m & 0xFull) == 0xFull) ? 1 : 0;
            __hip_atomic_store(&okv[b * 4 + q], 0x100u | (unsigned)okall,
                               __ATOMIC_RELAXED, __HIP_MEMORY_SCOPE_AGENT);
            int f = 1;
            #pragma unroll 1
            for (int i = 0; i < 4; ++i) {
                unsigned u;
                do {
                    u = __hip_atomic_load(&okv[b * 4 + i], __ATOMIC_RELAXED, __HIP_MEMORY_SCOPE_AGENT);
                } while (!(u & 0x100u));
                f &= (int)(u & 1u);
            }
            fast_sh = f;
        }
    }

    // ---- weights for rows jg0, jg0+1 over k in [64s,64s+64): 128 VGPRs ----
    float4 w0[16], w1[16];
    {
        const float* basek = WT + (size_t)(s * 64) * GD;
        #pragma unroll
        for (int i = 0; i < 16; ++i) {
            const float* p0 = basek + (size_t)(4 * i) * GD + jg0;
            w0[i] = make_float4(p0[0], p0[GD], p0[2 * GD], p0[3 * GD]);
            const float* p1 = p0 + 1;
            w1[i] = make_float4(p1[0], p1[GD], p1[2 * GD], p1[3 * GD]);
        }
    }
    const float wih0 = Wih[jg0], wih1 = Wih[jg0 + 1];
    const float bj0  = bias[jg0], bj1  = bias[jg0 + 1];

    for (int i = tid; i < TT; i += NT) x_s[i] = x[b * TT + i];
    if (tid < 256) {
        float hv = h_init ? h_init[((size_t)b * TT + (TT - 1)) * HD + tid] : 0.f;
        h_rep[tid >> 6][tid & 63] = hv;
    }
    float c = 0.f;   // live in wave q (tid in [64q,64q+64)) only
    __syncthreads();

    for (int t = 0; t < TT; ++t) {
        // ---- gate pre-activation partial over this thread's k-quarter ----
        // split accumulators: halve the serial FMA dependency chain
        const float xt = x_s[t];
        float a0p, a1p, a0q = 0.f, a1q = 0.f;
        if (s == 0) { a0p = fmaf(xt, wih0, bj0); a1p = fmaf(xt, wih1, bj1); }
        else        { a0p = 0.f;                 a1p = 0.f; }
        const float4* h4 = (const float4*)(&h_rep[s][0]);
        #pragma unroll
        for (int i = 0; i < 8; ++i) {
            float4 hv = h4[i];
            a0p = fmaf(hv.x, w0[i].x, a0p); a0p = fmaf(hv.y, w0[i].y, a0p);
            a0p = fmaf(hv.z, w0[i].z, a0p); a0p = fmaf(hv.w, w0[i].w, a0p);
            a1p = fmaf(hv.x, w1[i].x, a1p); a1p = fmaf(hv.y, w1[i].y, a1p);
            a1p = fmaf(hv.z, w1[i].z, a1p); a1p = fmaf(hv.w, w1[i].w, a1p);
        }
        #pragma unroll
        for (int i = 8; i < 16; ++i) {
            float4 hv = h4[i];
            a0q = fmaf(hv.x, w0[i].x, a0q); a0q = fmaf(hv.y, w0[i].y, a0q);
            a0q = fmaf(hv.z, w0[i].z, a0q); a0q = fmaf(hv.w, w0[i].w, a0q);
            a1q = fmaf(hv.x, w1[i].x, a1q); a1q = fmaf(hv.y, w1[i].y, a1q);
            a1q = fmaf(hv.z, w1[i].z, a1q); a1q = fmaf(hv.w, w1[i].w, a1q);
        }
        float a0 = a0p + a0q;
        float a1 = a1p + a1q;
        a0 += __shfl_xor(a0, 1); a0 += __shfl_xor(a0, 2);
        a1 += __shfl_xor(a1, 1); a1 += __shfl_xor(a1, 2);
        if (s == 0) {
            float2 av;
            av.x = (gate == 2) ? tanh_(a0) : sig_(a0);
            av.y = (gate == 2) ? tanh_(a1) : sig_(a1);
            *(float2*)(&act_s[r0]) = av;
        }
        __syncthreads();   // act ready (also orders fast_sh sticky writes)

        const unsigned tag = tag0 + (unsigned)t + 1u;
        unsigned long long* fsl = ex_fast + ((size_t)b * 2 + (t & 1)) * 256;
        unsigned long long* ssl = ex_slow + ((size_t)b * 2 + (t & 1)) * 256;
        if (tid < 256) {
            const int dq = tid >> 6, dk = tid & 63;   // wave-uniform dq
            if (dq == q) {
                float gi = act_s[dk], gf = act_s[64 + dk], gg = act_s[128 + dk], go = act_s[192 + dk];
                c = fmaf(gf, c, gi * gg);
                float h = go * tanh_(c);
                unsigned long long pk = ((unsigned long long)tag << 32)
                                      | (unsigned long long)__float_as_uint(h);
                // dual publish, fast first: plain store drains write-through L1 -> L2
                {
                    unsigned long long* fp2 = fsl + tid;
                    asm volatile("global_store_dwordx2 %0, %1, off"
                                 :: "v"(fp2), "v"(pk) : "memory");
                }
                __hip_atomic_store(&ssl[tid], pk, __ATOMIC_RELAXED, __HIP_MEMORY_SCOPE_AGENT);
                h_rep[q][dk] = h;
                states[((size_t)(b * TT + t)) * HD + tid] = h;
            } else {
                unsigned long long u;
                int got = 0;
                if (fast_sh) {
                    const unsigned long long* fp2 = fsl + tid;
                    #pragma unroll 1
                    for (int it = 0; it < STEP_SPINS; ++it) {
                        asm volatile("global_load_dwordx2 %0, %1, off sc0\n\ts_waitcnt vmcnt(0)"
                                     : "=&v"(u) : "v"(fp2) : "memory");
                        if ((unsigned)(u >> 32) == tag) { got = 1; break; }
                    }
                    if (!got) fast_sh = 0;   // sticky fallback: at most ONE timeout total
                }
                if (!got) {
                    do {
                        u = __hip_atomic_load(&ssl[tid], __ATOMIC_RELAXED, __HIP_MEMORY_SCOPE_AGENT);
                    } while ((unsigned)(u >> 32) != tag);
                }
                h_rep[dq][dk] = __uint_as_float((unsigned)u);
            }
        }
        __syncthreads();   // h replicas ready for t+1
    }
}

// ---------------- proj: ew[b][t]=E·w1, hw[b][t]=Hx·w2 (one wave per row) ----------------
__global__ __launch_bounds__(256) void proj_kernel(
    const float* __restrict__ enc_states, const float* __restrict__ dec_hs,
    const float* __restrict__ linW, float* __restrict__ ew, float* __restrict__ hw)
{
    const int lane = threadIdx.x & 63;
    const int wid  = blockIdx.x * 4 + (threadIdx.x >> 6);
    const int nw   = gridDim.x * 4;
    const float4 w1 = ((const float4*)linW)[lane];
    const float4 w2 = ((const float4*)(linW + HD))[lane];
    for (int o = wid; o < BB * TT; o += nw) {
        float4 v1 = ((const float4*)(enc_states + (size_t)o * HD))[lane];
        float4 v2 = ((const float4*)(dec_hs     + (size_t)o * HD))[lane];
        float s1 = v1.x * w1.x + v1.y * w1.y + v1.z * w1.z + v1.w * w1.w;
        float s2 = v2.x * w2.x + v2.y * w2.y + v2.z * w2.z + v2.w * w2.w;
        #pragma unroll
        for (int m = 1; m < 64; m <<= 1) {
            s1 += __shfl_xor(s1, m);
            s2 += __shfl_xor(s2, m);
        }
        if (lane == 0) { ew[o] = s1; hw[o] = s2; }
    }
}

// ---------------- attention v2: 32 td rows/block, 4x8 register tile ----------------
// Hx[k][td] stride 36 (16B-aligned rows): per k one wave-uniform ds_read_b128
// E[k][te]: lane-consecutive b32 reads (conflict-free, broadcast across td groups)
#define TD2  32    // td rows per block
#define TEC2 256   // te chunk
#define KC2  32    // k chunk
__global__ __launch_bounds__(256) void attn_kernel(
    const float* __restrict__ enc_states,  // [B][T][H]
    const float* __restrict__ dec_hs,      // [B][T][H]
    const float* __restrict__ ew, const float* __restrict__ hw,
    const float* __restrict__ lin_b,
    float* __restrict__ out)               // [B][T]
{
    const int b   = blockIdx.y;
    const int td0 = blockIdx.x * TD2;
    const int tid = threadIdx.x;
    const int tdt = tid >> 5;   // 0..7 (4 td rows each)
    const int tet = tid & 31;   // 0..31

    __shared__ float Hx[HD][TD2 + 4];   // stride 36: rows 16B-aligned
    __shared__ float E[KC2][TEC2];

    // stage Hx: thread -> (td = tid>>3, 32-k chunk = (tid&7)*32)
    {
        const int td = tid >> 3;
        const int kc = (tid & 7) * 32;
        const float* src = dec_hs + ((size_t)b * TT + td0 + td) * HD + kc;
        #pragma unroll
        for (int qq = 0; qq < 8; ++qq) {
            float4 v = ((const float4*)(src + qq * 4))[0];
            Hx[kc + qq * 4 + 0][td] = v.x;
            Hx[kc + qq * 4 + 1][td] = v.y;
            Hx[kc + qq * 4 + 2][td] = v.z;
            Hx[kc + qq * 4 + 3][td] = v.w;
        }
    }

    float M[4]  = {-1e30f, -1e30f, -1e30f, -1e30f};
    float Nm[4] = {0.f, 0.f, 0.f, 0.f};
    float Dn[4] = {0.f, 0.f, 0.f, 0.f};

    for (int tc = 0; tc < TT / TEC2; ++tc) {
        const int te0 = tc * TEC2;
        float S[4][8] = {{0.f}};
        for (int kc = 0; kc < HD / KC2; ++kc) {
            const int k0 = kc * KC2;
            __syncthreads();
            {   // stage E chunk: thread = te row, 32 consecutive k
                const float* src = enc_states + ((size_t)b * TT + te0 + tid) * HD + k0;
                #pragma unroll
                for (int qq = 0; qq < 8; ++qq) {
                    float4 v = ((const float4*)(src + qq * 4))[0];
                    E[qq * 4 + 0][tid] = v.x;
                    E[qq * 4 + 1][tid] = v.y;
                    E[qq * 4 + 2][tid] = v.z;
                    E[qq * 4 + 3][tid] = v.w;
                }
            }
            __syncthreads();
            #pragma unroll 4
            for (int k = 0; k < KC2; ++k) {
                const float4 hx4 = *(const float4*)(&Hx[k0 + k][tdt * 4]);
                #pragma unroll
                for (int i = 0; i < 8; ++i) {
                    const float e = E[k][tet + 32 * i];
                    S[0][i] = fmaf(hx4.x, e, S[0][i]);
                    S[1][i] = fmaf(hx4.y, e, S[1][i]);
                    S[2][i] = fmaf(hx4.z, e, S[2][i]);
                    S[3][i] = fmaf(hx4.w, e, S[3][i]);
                }
            }
        }
        float ewv[8];
        #pragma unroll
        for (int i = 0; i < 8; ++i) ewv[i] = ew[(size_t)b * TT + te0 + tet + 32 * i];
        #pragma unroll
        for (int r = 0; r < 4; ++r) {
            float cm = S[r][0];
            #pragma unroll
            for (int i = 1; i < 8; ++i) cm = fmaxf(cm, S[r][i]);
            #pragma unroll
            for (int m = 1; m < 32; m <<= 1) cm = fmaxf(cm, __shfl_xor(cm, m));
            const float newM  = fmaxf(M[r], cm);
            const float scale = __expf(M[r] - newM);
            float nl = 0.f, dl = 0.f;
            #pragma unroll
            for (int i = 0; i < 8; ++i) {
                const float p = __expf(S[r][i] - newM);
                dl += p;
                nl = fmaf(p, ewv[i], nl);
            }
            #pragma unroll
            for (int m = 1; m < 32; m <<= 1) {
                nl += __shfl_xor(nl, m);
                dl += __shfl_xor(dl, m);
            }
            Nm[r] = Nm[r] * scale + nl;
            Dn[r] = Dn[r] * scale + dl;
            M[r]  = newM;
        }
    }

    if (tet == 0) {
        const float lb = lin_b[0];
        #pragma unroll
        for (int r = 0; r < 4; ++r) {
            const int td = td0 + tdt * 4 + r;
            out[(size_t)b * TT + td] = Nm[r] / Dn[r] + hw[(size_t)b * TT + td] + lb;
        }
    }
}

extern "C" void kernel_launch(void* const* d_in, const int* in_sizes, int n_in,
                              void* d_out, int out_size, void* d_ws, size_t ws_size,
                              hipStream_t stream)
{
    const float* x    = (const float*)d_in[0];
    const float* eWih = (const float*)d_in[1];
    const float* eWhh = (const float*)d_in[2];
    const float* ebih = (const float*)d_in[3];
    const float* ebhh = (const float*)d_in[4];
    const float* dWih = (const float*)d_in[5];
    const float* dWhh = (const float*)d_in[6];
    const float* dbih = (const float*)d_in[7];
    const float* dbhh = (const float*)d_in[8];
    const float* linW = (const float*)d_in[9];
    const float* linb = (const float*)d_in[10];
    float* out = (float*)d_out;

    // ws layout: byte-identical to R4
    float* p = (float*)d_ws;
    float* WTe = p;        p += (size_t)GD * HD;
    float* WTd = p;        p += (size_t)GD * HD;
    float* be  = p;        p += GD;
    float* bd  = p;        p += GD;
    float* enc_states = p; p += (size_t)BB * TT * HD;
    float* dec_hs = p;     p += (size_t)BB * TT * HD;
    float* ew = p;         p += (size_t)BB * TT;
    float* hw = p;         p += (size_t)BB * TT;
    unsigned long long* ex_fast = (unsigned long long*)p; p += (size_t)BB * 2 * 256 * 2;
    unsigned long long* ex_slow = (unsigned long long*)p; p += (size_t)BB * 2 * 256 * 2;
    // probe + ok slots live in out[0:1024] (scratch; attn fully overwrites out)
    unsigned* pf_e = (unsigned*)out;       // 256
    unsigned* ok_e = pf_e + 256;           // 256
    unsigned* pf_d = pf_e + 512;           // 256
    unsigned* ok_d = pf_e + 768;           // 256

    prep_kernel<<<(GD * HD + 255) / 256, 256, 0, stream>>>(
        eWhh, ebih, ebhh, dWhh, dbih, dbhh, WTe, WTd, be, bd,
        ex_fast, (unsigned*)out);

    // A/B: encoder assumes round-robin placement, decoder assumes chunked.
    // Both normal launches (256 blocks <= 256 CUs => co-resident by capacity).
    lstm_scan_coop<<<256, NT, 0, stream>>>(
        x, eWih, be, WTe, nullptr, enc_states,
        ex_fast, ex_slow, pf_e, ok_e, 0u, 0);
    lstm_scan_coop<<<256, NT, 0, stream>>>(
        x, dWih, bd, WTd, enc_states, dec_hs,
        ex_fast, ex_slow, pf_d, ok_d, 1024u, 1);

    proj_kernel<<<256, 256, 0, stream>>>(enc_states, dec_hs, linW, ew, hw);
    attn_kernel<<<dim3(TT / TD2, BB), 256, 0, stream>>>(enc_states, dec_hs, ew, hw, linb, out);
}